// Round 3
// baseline (1022.825 us; speedup 1.0000x reference)
//
#include <hip/hip_runtime.h>
#include <math.h>

#define EPS 1e-6f

constexpr int B    = 8;
constexpr int F    = 64;
constexpr int C    = 16;
constexpr int L    = 65536;     // 256*256
constexpr int L2   = L / 2;     // float2 elements per (b, f) slice
constexpr int TPB  = 256;
constexpr int NREP = 8;         // atomic-target replicas to spread contention

// Stage 1: partials num[b,c] = sum_l (e2 - 2*dot)*r, den[b,c] = sum_l r.
// ws layout: float ws[NREP][2][2][B][C] -> [rep][term][num/den][b][c]
__global__ __launch_bounds__(TPB)
void cross_partial_kernel(const float* __restrict__ embed1,
                          const float* __restrict__ rids1,
                          const float* __restrict__ embed2,
                          const float* __restrict__ rids2,
                          const float* __restrict__ codebook,
                          float* __restrict__ ws)
{
    const int tid  = threadIdx.x;
    const int term = blockIdx.z;          // 0: (embed_1, r_ids_2), 1: (embed_2, r_ids_1)
    const int b    = blockIdx.y;
    const float* eptr = (term == 0) ? embed1 : embed2;
    const float* rptr = (term == 0) ? rids2  : rids1;

    const int g = blockIdx.x * TPB + tid;              // float2 index in [0, L2)
    const float2* eb = (const float2*)(eptr + (size_t)b * F * L) + g;
    const float2* rb = (const float2*)(rptr + (size_t)b * C * L) + g;

    float dotx[C], doty[C];
    #pragma unroll
    for (int c = 0; c < C; ++c) { dotx[c] = 0.f; doty[c] = 0.f; }
    float e2x = 0.f, e2y = 0.f;

    // batches of 8: force 8 float2 loads in flight before the fma block
    for (int fb = 0; fb < F; fb += 8) {
        float2 ev[8];
        #pragma unroll
        for (int u = 0; u < 8; ++u)
            ev[u] = eb[(size_t)(fb + u) * L2];
        #pragma unroll
        for (int u = 0; u < 8; ++u) {
            e2x = fmaf(ev[u].x, ev[u].x, e2x);
            e2y = fmaf(ev[u].y, ev[u].y, e2y);
            #pragma unroll
            for (int c = 0; c < C; ++c) {
                const float w = codebook[(fb + u) * C + c];   // wave-uniform -> SGPR
                dotx[c] = fmaf(ev[u].x, w, dotx[c]);
                doty[c] = fmaf(ev[u].y, w, doty[c]);
            }
        }
    }

    // fold r (batched loads), wave shuffle-reduce, block LDS reduce, one atomic per value
    float2 rv[C];
    #pragma unroll
    for (int c = 0; c < C; ++c)
        rv[c] = rb[(size_t)c * L2];

    const int lane = tid & 63, wid = tid >> 6;
    __shared__ float part[4][2][C];
    #pragma unroll
    for (int c = 0; c < C; ++c) {
        float num = fmaf(-2.f, dotx[c], e2x) * rv[c].x
                  + fmaf(-2.f, doty[c], e2y) * rv[c].y;
        float den = rv[c].x + rv[c].y;
        #pragma unroll
        for (int off = 32; off > 0; off >>= 1) {
            num += __shfl_down(num, off, 64);
            den += __shfl_down(den, off, 64);
        }
        if (lane == 0) { part[wid][0][c] = num; part[wid][1][c] = den; }
    }
    __syncthreads();
    if (tid < 2 * C) {
        const int p = tid >> 4, c = tid & 15;
        const float v = part[0][p][c] + part[1][p][c] + part[2][p][c] + part[3][p][c];
        const int rep = blockIdx.x & (NREP - 1);
        atomicAdd(ws + ((((size_t)rep * 2 + term) * 2 + p) * B + b) * C + c, v);
    }
}

// Stage 2: single block. cross = (num + cb2[c]*den)/(den+EPS); plus dist/reg losses.
__global__ __launch_bounds__(256)
void finalize_kernel(const float* __restrict__ codebook,
                     const float* __restrict__ ws,
                     float* __restrict__ out)
{
    __shared__ float cbs[F * C];
    __shared__ float cb2[C];
    __shared__ float red[256];
    __shared__ float redv[256];
    const int tid = threadIdx.x;
    ((float4*)cbs)[tid] = ((const float4*)codebook)[tid];
    __syncthreads();
    if (tid < C) {
        float s = 0.f;
        for (int f = 0; f < F; ++f) { const float v = cbs[f * C + tid]; s = fmaf(v, v, s); }
        cb2[tid] = s;
    }
    __syncthreads();

    // l_cross: 256 entries = [term(2)][b(8)][c(16)]
    {
        const int term = tid >> 7, rem = tid & 127;
        const int b = rem >> 4, c = rem & 15;
        float num = 0.f, den = 0.f;
        for (int rep = 0; rep < NREP; ++rep) {
            num += ws[((((size_t)rep * 2 + term) * 2 + 0) * B + b) * C + c];
            den += ws[((((size_t)rep * 2 + term) * 2 + 1) * B + b) * C + c];
        }
        const bool valid = (den != 0.f);
        red[tid]  = valid ? (num + cb2[c] * den) / (den + EPS) : 0.f;
        redv[tid] = valid ? 1.f : 0.f;
    }
    __syncthreads();
    if (tid == 0) {
        float s0 = 0.f, n0 = 0.f, s1 = 0.f, n1 = 0.f;
        for (int i = 0;   i < 128; ++i) { s0 += red[i]; n0 += redv[i]; }
        for (int i = 128; i < 256; ++i) { s1 += red[i]; n1 += redv[i]; }
        out[0] = s0 / n0 + s1 / n1;
    }
    __syncthreads();

    // l_dist: 256 (ci,cj) pairs, diagonal included exactly as reference
    {
        const int ci = tid & 15, cj = tid >> 4;
        float sq = 0.f;
        for (int f = 0; f < F; ++f) {
            const float d = cbs[f * C + ci] - cbs[f * C + cj];
            sq = fmaf(d, d, sq);
        }
        const float dist = (sq > 0.f) ? sqrtf(sq) : 0.f;
        const float h = fmaxf(2.f * 1.0f - dist, 0.f);
        red[tid] = h * h;
    }
    __syncthreads();
    if (tid == 0) {
        float s = 0.f;
        for (int i = 0; i < 256; ++i) s += red[i];
        out[1] = s / (2.f * C * (C - 1));
        float rg = 0.f;
        for (int c = 0; c < C; ++c) rg += sqrtf(cb2[c]);
        out[2] = rg / C;
    }
}

extern "C" void kernel_launch(void* const* d_in, const int* in_sizes, int n_in,
                              void* d_out, int out_size, void* d_ws, size_t ws_size,
                              hipStream_t stream)
{
    const float* e1 = (const float*)d_in[0];
    const float* r1 = (const float*)d_in[1];
    const float* e2 = (const float*)d_in[2];
    const float* r2 = (const float*)d_in[3];
    const float* cb = (const float*)d_in[4];
    float* out = (float*)d_out;
    float* ws  = (float*)d_ws;

    // zero the NREP*2*2*B*C accumulator block (16 KB)
    hipMemsetAsync(ws, 0, (size_t)NREP * 2 * 2 * B * C * sizeof(float), stream);

    dim3 grid(L2 / TPB, B, 2);   // 128 x 8 x 2 = 2048 blocks = 8192 waves = 32 waves/CU
    cross_partial_kernel<<<grid, TPB, 0, stream>>>(e1, r1, e2, r2, cb, ws);
    finalize_kernel<<<1, 256, 0, stream>>>(cb, ws, out);
}

// Round 4
// 376.680 us; speedup vs baseline: 2.7154x; 2.7154x over previous
//
#include <hip/hip_runtime.h>
#include <math.h>

#define EPS 1e-6f

constexpr int B    = 8;
constexpr int F    = 64;
constexpr int C    = 16;
constexpr int L    = 65536;     // 256*256
constexpr int G4   = L / 4;     // float4 elements per (b, f) slice
constexpr int TPB  = 256;
constexpr int NREP = 8;         // atomic-target replicas to spread contention

// Stage 1: partials num[b,c] = sum_l (e2 - 2*dot)*r, den[b,c] = sum_l r.
// ws layout: float ws[NREP][2][2][B][C] -> [rep][term][num/den][b][c]
//
// Wave w of each block owns codebook columns c in [4w, 4w+4): accumulators are
// dot[4][4] + e2[4] = 20 VGPRs, keeping total allocation < 64 (8 waves/SIMD).
// All 4 waves read the same e float4 range (L1 broadcast); HBM reads stay 1x.
__global__ __launch_bounds__(TPB)
void cross_partial_kernel(const float* __restrict__ embed1,
                          const float* __restrict__ rids1,
                          const float* __restrict__ embed2,
                          const float* __restrict__ rids2,
                          const float* __restrict__ codebook,
                          float* __restrict__ ws)
{
    const int tid  = threadIdx.x;
    const int lane = tid & 63;
    const int wid  = tid >> 6;
    const int term = blockIdx.z;          // 0: (embed_1, r_ids_2), 1: (embed_2, r_ids_1)
    const int b    = blockIdx.y;
    const float* eptr = (term == 0) ? embed1 : embed2;
    const float* rptr = (term == 0) ? rids2  : rids1;

    // force wave-uniform c-base into an SGPR so codebook reads become s_load
    const int c0 = __builtin_amdgcn_readfirstlane(wid * 4);

    const int g = blockIdx.x * 64 + lane;              // float4 index in [0, G4)
    const float4* eb = (const float4*)(eptr + (size_t)b * F * L) + g;
    const float4* rb = (const float4*)(rptr + (size_t)b * C * L) + g;

    float dot[4][4];
    #pragma unroll
    for (int j = 0; j < 4; ++j)
        dot[j][0] = dot[j][1] = dot[j][2] = dot[j][3] = 0.f;
    float e2x = 0.f, e2y = 0.f, e2z = 0.f, e2w = 0.f;

    // 2-deep prefetch: ~2 KB in flight per wave, 32 waves/CU -> BW-bound
    float4 cur = eb[0];
    #pragma unroll
    for (int f = 0; f < F; ++f) {
        float4 nxt = make_float4(0.f, 0.f, 0.f, 0.f);
        if (f + 1 < F) nxt = eb[(size_t)(f + 1) * G4];
        e2x = fmaf(cur.x, cur.x, e2x);
        e2y = fmaf(cur.y, cur.y, e2y);
        e2z = fmaf(cur.z, cur.z, e2z);
        e2w = fmaf(cur.w, cur.w, e2w);
        #pragma unroll
        for (int j = 0; j < 4; ++j) {
            const float w = codebook[f * C + c0 + j];   // wave-uniform -> s_load
            dot[j][0] = fmaf(cur.x, w, dot[j][0]);
            dot[j][1] = fmaf(cur.y, w, dot[j][1]);
            dot[j][2] = fmaf(cur.z, w, dot[j][2]);
            dot[j][3] = fmaf(cur.w, w, dot[j][3]);
        }
        cur = nxt;
    }

    // epilogue: issue all 4 r loads together, fold, wave-reduce, atomics.
    float4 rv[4];
    #pragma unroll
    for (int j = 0; j < 4; ++j)
        rv[j] = rb[(size_t)(c0 + j) * G4];

    const int rep = blockIdx.x & (NREP - 1);
    float* wsn = ws + ((((size_t)rep * 2 + term) * 2 + 0) * B + b) * C;
    float* wsd = ws + ((((size_t)rep * 2 + term) * 2 + 1) * B + b) * C;
    #pragma unroll
    for (int j = 0; j < 4; ++j) {
        const float sx = fmaf(-2.f, dot[j][0], e2x);
        const float sy = fmaf(-2.f, dot[j][1], e2y);
        const float sz = fmaf(-2.f, dot[j][2], e2z);
        const float sw = fmaf(-2.f, dot[j][3], e2w);
        float num = fmaf(sx, rv[j].x, fmaf(sy, rv[j].y, fmaf(sz, rv[j].z, sw * rv[j].w)));
        float den = (rv[j].x + rv[j].y) + (rv[j].z + rv[j].w);
        #pragma unroll
        for (int off = 32; off > 0; off >>= 1) {
            num += __shfl_down(num, off, 64);
            den += __shfl_down(den, off, 64);
        }
        if (lane == 0) {
            atomicAdd(&wsn[c0 + j], num);
            atomicAdd(&wsd[c0 + j], den);
        }
    }
}

// Stage 2: single block. cross = (num + cb2[c]*den)/(den+EPS); plus dist/reg losses.
__global__ __launch_bounds__(256)
void finalize_kernel(const float* __restrict__ codebook,
                     const float* __restrict__ ws,
                     float* __restrict__ out)
{
    __shared__ float cbs[F * C];
    __shared__ float cb2[C];
    __shared__ float red[256];
    __shared__ float redv[256];
    const int tid = threadIdx.x;
    ((float4*)cbs)[tid] = ((const float4*)codebook)[tid];
    __syncthreads();
    if (tid < C) {
        float s = 0.f;
        for (int f = 0; f < F; ++f) { const float v = cbs[f * C + tid]; s = fmaf(v, v, s); }
        cb2[tid] = s;
    }
    __syncthreads();

    // l_cross: 256 entries = [term(2)][b(8)][c(16)]
    {
        const int term = tid >> 7, rem = tid & 127;
        const int b = rem >> 4, c = rem & 15;
        float num = 0.f, den = 0.f;
        for (int rep = 0; rep < NREP; ++rep) {
            num += ws[((((size_t)rep * 2 + term) * 2 + 0) * B + b) * C + c];
            den += ws[((((size_t)rep * 2 + term) * 2 + 1) * B + b) * C + c];
        }
        const bool valid = (den != 0.f);
        red[tid]  = valid ? (num + cb2[c] * den) / (den + EPS) : 0.f;
        redv[tid] = valid ? 1.f : 0.f;
    }
    __syncthreads();
    if (tid == 0) {
        float s0 = 0.f, n0 = 0.f, s1 = 0.f, n1 = 0.f;
        for (int i = 0;   i < 128; ++i) { s0 += red[i]; n0 += redv[i]; }
        for (int i = 128; i < 256; ++i) { s1 += red[i]; n1 += redv[i]; }
        out[0] = s0 / n0 + s1 / n1;
    }
    __syncthreads();

    // l_dist: 256 (ci,cj) pairs, diagonal included exactly as reference
    {
        const int ci = tid & 15, cj = tid >> 4;
        float sq = 0.f;
        for (int f = 0; f < F; ++f) {
            const float d = cbs[f * C + ci] - cbs[f * C + cj];
            sq = fmaf(d, d, sq);
        }
        const float dist = (sq > 0.f) ? sqrtf(sq) : 0.f;
        const float h = fmaxf(2.f * 1.0f - dist, 0.f);
        red[tid] = h * h;
    }
    __syncthreads();
    if (tid == 0) {
        float s = 0.f;
        for (int i = 0; i < 256; ++i) s += red[i];
        out[1] = s / (2.f * C * (C - 1));
        float rg = 0.f;
        for (int c = 0; c < C; ++c) rg += sqrtf(cb2[c]);
        out[2] = rg / C;
    }
}

extern "C" void kernel_launch(void* const* d_in, const int* in_sizes, int n_in,
                              void* d_out, int out_size, void* d_ws, size_t ws_size,
                              hipStream_t stream)
{
    const float* e1 = (const float*)d_in[0];
    const float* r1 = (const float*)d_in[1];
    const float* e2 = (const float*)d_in[2];
    const float* r2 = (const float*)d_in[3];
    const float* cb = (const float*)d_in[4];
    float* out = (float*)d_out;
    float* ws  = (float*)d_ws;

    // zero the NREP*2*2*B*C accumulator block (16 KB)
    hipMemsetAsync(ws, 0, (size_t)NREP * 2 * 2 * B * C * sizeof(float), stream);

    // block covers 256 spatial points (64 lanes x float4), 4 waves = 4 c-groups
    dim3 grid(G4 / 64, B, 2);    // 256 x 8 x 2 = 4096 blocks
    cross_partial_kernel<<<grid, TPB, 0, stream>>>(e1, r1, e2, r2, cb, ws);
    finalize_kernel<<<1, 256, 0, stream>>>(cb, ws, out);
}

// Round 5
// 83.447 us; speedup vs baseline: 12.2573x; 4.5140x over previous
//
#include <hip/hip_runtime.h>
#include <math.h>

#define EPS 1e-6f

constexpr int B    = 8;
constexpr int F    = 64;
constexpr int C    = 16;
constexpr int L    = 65536;     // 256*256
constexpr int L2   = L / 2;     // float2 elements per (b, f) slice
constexpr int TPB  = 256;
constexpr int NREP = 8;         // atomic-target replicas to spread contention

// Stage 1: partials num[b,c] = sum_l (e2 - 2*dot)*r, den[b,c] = sum_l r.
// ws layout: float ws[NREP][2][2][B][C] -> [rep][term][num/den][b][c]
//
// Register-pressure design (the lesson of R1-R4): __launch_bounds__(256,8)
// hard-caps at 64 VGPR (8 blocks/CU = 32 waves/CU). Each wave owns 8 of the
// 16 codebook columns (wave pairs re-read the same e-slice; 2nd read is an
// L1 hit, HBM unchanged), so accumulators are dotx[8]+doty[8]+e2{x,y} = 18
// regs; the explicit ev[4] float2 batch adds 8 and guarantees 4 loads in
// flight per wave. ~50 VGPR total -> no spills, full occupancy, 4-deep ILP.
__global__ __launch_bounds__(TPB, 8)
void cross_partial_kernel(const float* __restrict__ embed1,
                          const float* __restrict__ rids1,
                          const float* __restrict__ embed2,
                          const float* __restrict__ rids2,
                          const float* __restrict__ codebook,
                          float* __restrict__ ws)
{
    const int tid   = threadIdx.x;
    const int lane  = tid & 63;
    const int wid   = tid >> 6;
    const int gslot = wid >> 1;           // which 64-float2 chunk of the block's range
    const int term  = blockIdx.z;         // 0: (embed_1, r_ids_2), 1: (embed_2, r_ids_1)
    const int b     = blockIdx.y;
    const float* eptr = (term == 0) ? embed1 : embed2;
    const float* rptr = (term == 0) ? rids2  : rids1;

    // wave-uniform c-base in an SGPR so codebook reads become s_load
    const int c0 = __builtin_amdgcn_readfirstlane((wid & 1) * 8);

    const int g = blockIdx.x * 128 + gslot * 64 + lane;   // float2 index in [0, L2)
    const float2* eb = (const float2*)(eptr + (size_t)b * F * L) + g;
    const float2* rb = (const float2*)(rptr + (size_t)b * C * L) + g;

    float dotx[8], doty[8];
    #pragma unroll
    for (int j = 0; j < 8; ++j) { dotx[j] = 0.f; doty[j] = 0.f; }
    float e2x = 0.f, e2y = 0.f;

    #pragma unroll 1
    for (int fb = 0; fb < F; fb += 4) {
        float2 ev[4];
        #pragma unroll
        for (int u = 0; u < 4; ++u)
            ev[u] = eb[(size_t)(fb + u) * L2];
        #pragma unroll
        for (int u = 0; u < 4; ++u) {
            e2x = fmaf(ev[u].x, ev[u].x, e2x);
            e2y = fmaf(ev[u].y, ev[u].y, e2y);
            #pragma unroll
            for (int j = 0; j < 8; ++j) {
                const float w = codebook[(fb + u) * C + c0 + j];  // SGPR broadcast
                dotx[j] = fmaf(ev[u].x, w, dotx[j]);
                doty[j] = fmaf(ev[u].y, w, doty[j]);
            }
        }
    }

    // epilogue: r loads in batches of 4 (in flight together), fold, wave-reduce
    __shared__ float part[4][2][8];
    #pragma unroll 1
    for (int jb = 0; jb < 8; jb += 4) {
        float2 rv[4];
        #pragma unroll
        for (int u = 0; u < 4; ++u)
            rv[u] = rb[(size_t)(c0 + jb + u) * L2];
        #pragma unroll
        for (int u = 0; u < 4; ++u) {
            const int j = jb + u;
            float num = fmaf(-2.f, dotx[j], e2x) * rv[u].x
                      + fmaf(-2.f, doty[j], e2y) * rv[u].y;
            float den = rv[u].x + rv[u].y;
            #pragma unroll
            for (int off = 32; off > 0; off >>= 1) {
                num += __shfl_down(num, off, 64);
                den += __shfl_down(den, off, 64);
            }
            if (lane == 0) { part[wid][0][j] = num; part[wid][1][j] = den; }
        }
    }
    __syncthreads();

    // combine the two gslot waves per c, one atomic per value
    if (tid < 2 * C) {
        const int p = tid >> 4, c = tid & 15;
        const int chalf = c >> 3, j = c & 7;
        const float v = part[chalf][p][j] + part[chalf + 2][p][j];
        const int rep = blockIdx.x & (NREP - 1);
        atomicAdd(ws + ((((size_t)rep * 2 + term) * 2 + p) * B + b) * C + c, v);
    }
}

// Stage 2: single block. cross = (num + cb2[c]*den)/(den+EPS); plus dist/reg losses.
__global__ __launch_bounds__(256)
void finalize_kernel(const float* __restrict__ codebook,
                     const float* __restrict__ ws,
                     float* __restrict__ out)
{
    __shared__ float cbs[F * C];
    __shared__ float cb2[C];
    __shared__ float red[256];
    __shared__ float redv[256];
    const int tid = threadIdx.x;
    ((float4*)cbs)[tid] = ((const float4*)codebook)[tid];
    __syncthreads();
    if (tid < C) {
        float s = 0.f;
        for (int f = 0; f < F; ++f) { const float v = cbs[f * C + tid]; s = fmaf(v, v, s); }
        cb2[tid] = s;
    }
    __syncthreads();

    // l_cross: 256 entries = [term(2)][b(8)][c(16)]
    {
        const int term = tid >> 7, rem = tid & 127;
        const int b = rem >> 4, c = rem & 15;
        float num = 0.f, den = 0.f;
        for (int rep = 0; rep < NREP; ++rep) {
            num += ws[((((size_t)rep * 2 + term) * 2 + 0) * B + b) * C + c];
            den += ws[((((size_t)rep * 2 + term) * 2 + 1) * B + b) * C + c];
        }
        const bool valid = (den != 0.f);
        red[tid]  = valid ? (num + cb2[c] * den) / (den + EPS) : 0.f;
        redv[tid] = valid ? 1.f : 0.f;
    }
    __syncthreads();
    if (tid == 0) {
        float s0 = 0.f, n0 = 0.f, s1 = 0.f, n1 = 0.f;
        for (int i = 0;   i < 128; ++i) { s0 += red[i]; n0 += redv[i]; }
        for (int i = 128; i < 256; ++i) { s1 += red[i]; n1 += redv[i]; }
        out[0] = s0 / n0 + s1 / n1;
    }
    __syncthreads();

    // l_dist: 256 (ci,cj) pairs, diagonal included exactly as reference
    {
        const int ci = tid & 15, cj = tid >> 4;
        float sq = 0.f;
        for (int f = 0; f < F; ++f) {
            const float d = cbs[f * C + ci] - cbs[f * C + cj];
            sq = fmaf(d, d, sq);
        }
        const float dist = (sq > 0.f) ? sqrtf(sq) : 0.f;
        const float h = fmaxf(2.f * 1.0f - dist, 0.f);
        red[tid] = h * h;
    }
    __syncthreads();
    if (tid == 0) {
        float s = 0.f;
        for (int i = 0; i < 256; ++i) s += red[i];
        out[1] = s / (2.f * C * (C - 1));
        float rg = 0.f;
        for (int c = 0; c < C; ++c) rg += sqrtf(cb2[c]);
        out[2] = rg / C;
    }
}

extern "C" void kernel_launch(void* const* d_in, const int* in_sizes, int n_in,
                              void* d_out, int out_size, void* d_ws, size_t ws_size,
                              hipStream_t stream)
{
    const float* e1 = (const float*)d_in[0];
    const float* r1 = (const float*)d_in[1];
    const float* e2 = (const float*)d_in[2];
    const float* r2 = (const float*)d_in[3];
    const float* cb = (const float*)d_in[4];
    float* out = (float*)d_out;
    float* ws  = (float*)d_ws;

    // zero the NREP*2*2*B*C accumulator block (16 KB)
    hipMemsetAsync(ws, 0, (size_t)NREP * 2 * 2 * B * C * sizeof(float), stream);

    // block covers 128 float2 (2 gslots x 64 lanes); wave pairs split C 8+8
    dim3 grid(L2 / 128, B, 2);   // 256 x 8 x 2 = 4096 blocks = 16384 waves
    cross_partial_kernel<<<grid, TPB, 0, stream>>>(e1, r1, e2, r2, cb, ws);
    finalize_kernel<<<1, 256, 0, stream>>>(cb, ws, out);
}

// Round 6
// 79.489 us; speedup vs baseline: 12.8676x; 1.0498x over previous
//
#include <hip/hip_runtime.h>
#include <math.h>

#define EPS 1e-6f

constexpr int B    = 8;
constexpr int F    = 64;
constexpr int C    = 16;
constexpr int L    = 65536;     // 256*256
constexpr int L2   = L / 2;     // float2 elements per (b, f) slice
constexpr int TPB  = 256;
constexpr int NREP = 8;         // atomic-target replicas to spread contention

// Stage 1: partials num[b,c] = sum_l (e2 - 2*dot)*r, den[b,c] = sum_l r.
// ws layout: float ws[NREP][2][2][B][C] -> [rep][term][num/den][b][c]
//
// R5 lesson: VGPR=20 proved the compiler collapsed the ev[] batch to ~1-2
// outstanding loads (18 accum regs + 2 reused temps). Fix: batch 8 float2
// loads and pin them with sched_barrier(0) so all 8 issue before any use
// (4 KB in flight per wave, ~24-32 KB/CU >= 3x BW*latency). launch_bounds
// (256,8) keeps the 64-VGPR cap that gave R5 its 76% occupancy.
__global__ __launch_bounds__(TPB, 8)
void cross_partial_kernel(const float* __restrict__ embed1,
                          const float* __restrict__ rids1,
                          const float* __restrict__ embed2,
                          const float* __restrict__ rids2,
                          const float* __restrict__ codebook,
                          float* __restrict__ ws)
{
    const int tid   = threadIdx.x;
    const int lane  = tid & 63;
    const int wid   = tid >> 6;
    const int gslot = wid >> 1;           // which 64-float2 chunk of the block's range
    const int term  = blockIdx.z;         // 0: (embed_1, r_ids_2), 1: (embed_2, r_ids_1)
    const int b     = blockIdx.y;
    const float* eptr = (term == 0) ? embed1 : embed2;
    const float* rptr = (term == 0) ? rids2  : rids1;

    // wave-uniform c-base in an SGPR so codebook reads become s_load
    const int c0 = __builtin_amdgcn_readfirstlane((wid & 1) * 8);

    const int g = blockIdx.x * 128 + gslot * 64 + lane;   // float2 index in [0, L2)
    const float2* eb = (const float2*)(eptr + (size_t)b * F * L) + g;
    const float2* rb = (const float2*)(rptr + (size_t)b * C * L) + g;

    float dotx[8], doty[8];
    #pragma unroll
    for (int j = 0; j < 8; ++j) { dotx[j] = 0.f; doty[j] = 0.f; }
    float e2x = 0.f, e2y = 0.f;

    #pragma unroll 1
    for (int fb = 0; fb < F; fb += 8) {
        float2 ev[8];
        #pragma unroll
        for (int u = 0; u < 8; ++u)
            ev[u] = eb[(size_t)(fb + u) * L2];
        // pin: all 8 loads issue before any consumer -> 8 in flight, 16 regs held
        __builtin_amdgcn_sched_barrier(0);
        #pragma unroll
        for (int u = 0; u < 8; ++u) {
            e2x = fmaf(ev[u].x, ev[u].x, e2x);
            e2y = fmaf(ev[u].y, ev[u].y, e2y);
            #pragma unroll
            for (int j = 0; j < 8; ++j) {
                const float w = codebook[(fb + u) * C + c0 + j];  // SGPR broadcast
                dotx[j] = fmaf(ev[u].x, w, dotx[j]);
                doty[j] = fmaf(ev[u].y, w, doty[j]);
            }
        }
    }

    // epilogue: all 8 r loads in flight together, fold, wave-reduce
    __shared__ float part[4][2][8];
    {
        float2 rv[8];
        #pragma unroll
        for (int j = 0; j < 8; ++j)
            rv[j] = rb[(size_t)(c0 + j) * L2];
        __builtin_amdgcn_sched_barrier(0);
        #pragma unroll
        for (int j = 0; j < 8; ++j) {
            float num = fmaf(-2.f, dotx[j], e2x) * rv[j].x
                      + fmaf(-2.f, doty[j], e2y) * rv[j].y;
            float den = rv[j].x + rv[j].y;
            #pragma unroll
            for (int off = 32; off > 0; off >>= 1) {
                num += __shfl_down(num, off, 64);
                den += __shfl_down(den, off, 64);
            }
            if (lane == 0) { part[wid][0][j] = num; part[wid][1][j] = den; }
        }
    }
    __syncthreads();

    // combine the two gslot waves per c, one atomic per value
    if (tid < 2 * C) {
        const int p = tid >> 4, c = tid & 15;
        const int chalf = c >> 3, j = c & 7;
        const float v = part[chalf][p][j] + part[chalf + 2][p][j];
        const int rep = blockIdx.x & (NREP - 1);
        atomicAdd(ws + ((((size_t)rep * 2 + term) * 2 + p) * B + b) * C + c, v);
    }
}

// Stage 2: single block. cross = (num + cb2[c]*den)/(den+EPS); plus dist/reg losses.
__global__ __launch_bounds__(256)
void finalize_kernel(const float* __restrict__ codebook,
                     const float* __restrict__ ws,
                     float* __restrict__ out)
{
    __shared__ float cbs[F * C];
    __shared__ float cb2[C];
    __shared__ float red[256];
    __shared__ float redv[256];
    const int tid = threadIdx.x;
    ((float4*)cbs)[tid] = ((const float4*)codebook)[tid];
    __syncthreads();
    if (tid < C) {
        float s = 0.f;
        for (int f = 0; f < F; ++f) { const float v = cbs[f * C + tid]; s = fmaf(v, v, s); }
        cb2[tid] = s;
    }
    __syncthreads();

    // l_cross: 256 entries = [term(2)][b(8)][c(16)]
    {
        const int term = tid >> 7, rem = tid & 127;
        const int b = rem >> 4, c = rem & 15;
        float num = 0.f, den = 0.f;
        for (int rep = 0; rep < NREP; ++rep) {
            num += ws[((((size_t)rep * 2 + term) * 2 + 0) * B + b) * C + c];
            den += ws[((((size_t)rep * 2 + term) * 2 + 1) * B + b) * C + c];
        }
        const bool valid = (den != 0.f);
        red[tid]  = valid ? (num + cb2[c] * den) / (den + EPS) : 0.f;
        redv[tid] = valid ? 1.f : 0.f;
    }
    __syncthreads();
    if (tid == 0) {
        float s0 = 0.f, n0 = 0.f, s1 = 0.f, n1 = 0.f;
        for (int i = 0;   i < 128; ++i) { s0 += red[i]; n0 += redv[i]; }
        for (int i = 128; i < 256; ++i) { s1 += red[i]; n1 += redv[i]; }
        out[0] = s0 / n0 + s1 / n1;
    }
    __syncthreads();

    // l_dist: 256 (ci,cj) pairs, diagonal included exactly as reference
    {
        const int ci = tid & 15, cj = tid >> 4;
        float sq = 0.f;
        for (int f = 0; f < F; ++f) {
            const float d = cbs[f * C + ci] - cbs[f * C + cj];
            sq = fmaf(d, d, sq);
        }
        const float dist = (sq > 0.f) ? sqrtf(sq) : 0.f;
        const float h = fmaxf(2.f * 1.0f - dist, 0.f);
        red[tid] = h * h;
    }
    __syncthreads();
    if (tid == 0) {
        float s = 0.f;
        for (int i = 0; i < 256; ++i) s += red[i];
        out[1] = s / (2.f * C * (C - 1));
        float rg = 0.f;
        for (int c = 0; c < C; ++c) rg += sqrtf(cb2[c]);
        out[2] = rg / C;
    }
}

extern "C" void kernel_launch(void* const* d_in, const int* in_sizes, int n_in,
                              void* d_out, int out_size, void* d_ws, size_t ws_size,
                              hipStream_t stream)
{
    const float* e1 = (const float*)d_in[0];
    const float* r1 = (const float*)d_in[1];
    const float* e2 = (const float*)d_in[2];
    const float* r2 = (const float*)d_in[3];
    const float* cb = (const float*)d_in[4];
    float* out = (float*)d_out;
    float* ws  = (float*)d_ws;

    // zero the NREP*2*2*B*C accumulator block (16 KB)
    hipMemsetAsync(ws, 0, (size_t)NREP * 2 * 2 * B * C * sizeof(float), stream);

    // block covers 128 float2 (2 gslots x 64 lanes); wave pairs split C 8+8
    dim3 grid(L2 / 128, B, 2);   // 256 x 8 x 2 = 4096 blocks = 16384 waves
    cross_partial_kernel<<<grid, TPB, 0, stream>>>(e1, r1, e2, r2, cb, ws);
    finalize_kernel<<<1, 256, 0, stream>>>(cb, ws, out);
}